// Round 7
// baseline (253.685 us; speedup 1.0000x reference)
//
#include <hip/hip_runtime.h>

typedef __attribute__((ext_vector_type(8))) short short8;
typedef __attribute__((ext_vector_type(8))) unsigned short ushort8v;
typedef __attribute__((ext_vector_type(4))) float f32x4;

#define N_NODES 4096
#define N_FEAT  256

__device__ __forceinline__ unsigned short f2bf(float f) {
  union { float f; unsigned u; } a; a.f = f;
  unsigned r = a.u + 0x7FFFu + ((a.u >> 16) & 1u);  // round-to-nearest-even
  return (unsigned short)(r >> 16);
}

__device__ __forceinline__ void gload_lds16(const void* g, void* l) {
  __builtin_amdgcn_global_load_lds(
      (const __attribute__((address_space(1))) void*)g,
      (__attribute__((address_space(3))) void*)l, 16, 0, 0);
}

// ---------------------------------------------------------------- spectrum
__global__ void spectrum_k(const float* __restrict__ lam, const float* __restrict__ tp,
                           float* __restrict__ cbuf, float* __restrict__ p2buf) {
  int i = blockIdx.x * 256 + threadIdx.x;
  float tv = tp[0];
  float s = sqrtf(fmaxf(lam[i], 0.f));
  cbuf[i] = cosf(tv * s);
  p2buf[i] = (s < 1e-5f) ? tv : (sinf(tv * s) / s);
}

// ---------------- fused prep: blocks [0,4096) do V->Vbf+Vt; [4096,4352) do x,y->S2T
__global__ __launch_bounds__(256) void prep_all_k(const float* __restrict__ V,
                                                  const float* __restrict__ x,
                                                  const float* __restrict__ y,
                                                  unsigned short* __restrict__ Vbf,
                                                  unsigned short* __restrict__ Vt,
                                                  unsigned short* __restrict__ S2T) {
  __shared__ unsigned short smem[2][64][72];
  const int t = threadIdx.x;
  const int r = t >> 2, q = t & 3;
  const unsigned b = blockIdx.x;
  if (b < 4096u) {
    // ---- prep_v: 64x64 tile transpose + convert
    const int bx = b & 63, by = b >> 6;
    const int gr = by * 64 + r;
    const int gc0 = bx * 64;
#pragma unroll
    for (int i = 0; i < 4; ++i) {
      int c = q * 4 + i * 16;
      float4 v = *(const float4*)&V[(size_t)gr * N_NODES + gc0 + c];
      ushort4 u; u.x = f2bf(v.x); u.y = f2bf(v.y); u.z = f2bf(v.z); u.w = f2bf(v.w);
      *(ushort4*)&Vbf[(size_t)gr * N_NODES + gc0 + c] = u;
      smem[0][c + 0][r] = u.x; smem[0][c + 1][r] = u.y;
      smem[0][c + 2][r] = u.z; smem[0][c + 3][r] = u.w;
    }
    __syncthreads();
    const int r2 = t >> 2;  // transposed row = V column
#pragma unroll
    for (int j = 0; j < 2; ++j) {
      int ms = q * 8 + j * 32;
      ushort8v u = *(const ushort8v*)&smem[0][r2][ms];
      *(ushort8v*)&Vt[(size_t)(gc0 + r2) * N_NODES + by * 64 + ms] = u;
    }
  } else {
    // ---- prep_xy: S2T[2f+s][j] = (s?y:x)[j][f]
    const unsigned b2 = b - 4096u;
    const int bx = b2 & 3, by = b2 >> 2;
    const int gj = by * 64 + r;
    const int gf0 = bx * 64;
#pragma unroll
    for (int i = 0; i < 4; ++i) {
      int c = q * 4 + i * 16;
      float4 vx = *(const float4*)&x[(size_t)gj * N_FEAT + gf0 + c];
      float4 vy = *(const float4*)&y[(size_t)gj * N_FEAT + gf0 + c];
      smem[0][c + 0][r] = f2bf(vx.x); smem[0][c + 1][r] = f2bf(vx.y);
      smem[0][c + 2][r] = f2bf(vx.z); smem[0][c + 3][r] = f2bf(vx.w);
      smem[1][c + 0][r] = f2bf(vy.x); smem[1][c + 1][r] = f2bf(vy.y);
      smem[1][c + 2][r] = f2bf(vy.z); smem[1][c + 3][r] = f2bf(vy.w);
    }
    __syncthreads();
    const int f2 = t >> 2;
#pragma unroll
    for (int j = 0; j < 2; ++j) {
      int js = q * 8 + j * 32;
      ushort8v ux = *(const ushort8v*)&smem[0][f2][js];
      ushort8v uy = *(const ushort8v*)&smem[1][f2][js];
      *(ushort8v*)&S2T[(size_t)(2 * (gf0 + f2) + 0) * N_NODES + by * 64 + js] = ux;
      *(ushort8v*)&S2T[(size_t)(2 * (gf0 + f2) + 1) * N_NODES + by * 64 + js] = uy;
    }
  }
}

// --------------------------------------------------------------- split-K GEMM
// BM=128, BN=128, BK=64, 256 threads (4 waves 2x2), wave tile 64x64 (acc[4][4]).
// Single-buffered LDS (32 KB), 4 blocks/CU. XOR slot-swizzle via pre-swizzled
// global source (LDS dest linear for global_load_lds). XCD-bijective remap.
// Epilogue: f32 atomicAdd accumulation into `out` (zero-initialized). SCALE=true
// (gemm1) multiplies by c[m] (even n = x path) / p2[m] (odd n = y path) first —
// the scale commutes with the K-sum, so per-slice scaling is exact.
template <int NTB, bool SCALE>
__global__ __launch_bounds__(256, 4) void gemm_swz(const unsigned short* __restrict__ A,
                                                   const unsigned short* __restrict__ B,
                                                   float* __restrict__ out,
                                                   const float* __restrict__ cbuf,
                                                   const float* __restrict__ p2buf,
                                                   int K, int Kc, int Nn) {
  __shared__ unsigned short As[128 * 64];
  __shared__ unsigned short Bs[128 * 64];
  const int t = threadIdx.x;
  const int lane = t & 63, w = t >> 6;

  const unsigned L = blockIdx.x;
  const unsigned cx = L & 7u, j = L >> 3u;
  const unsigned ntile = j & ((1u << NTB) - 1u);
  const unsigned GPX = (gridDim.x >> 3) >> NTB;
  const unsigned group = cx * GPX + (j >> NTB);
  const unsigned mtile = group & 31u;
  const unsigned zz = group >> 5u;

  const int wr = (w >> 1) * 64;
  const int wc = (w & 1) * 64;
  const int l15 = lane & 15;
  const int lhi = lane >> 4;

  const size_t kbase = (size_t)zz * Kc;
  // pre-swizzled per-lane source offset (bytes): row lane>>3, k-slot (lane&7)^(lane>>3)
  const size_t srcoff = (size_t)(lane >> 3) * K * 2 + (size_t)(((lane & 7) ^ (lane >> 3)) << 4);

  const char* Ag = (const char*)(A + (size_t)mtile * 128 * K + kbase);
  const char* Bg = (const char*)(B + (size_t)ntile * 128 * K + kbase);

  f32x4 acc[4][4];
#pragma unroll
  for (int mi = 0; mi < 4; ++mi)
#pragma unroll
    for (int ni = 0; ni < 4; ++ni) acc[mi][ni] = (f32x4){0.f, 0.f, 0.f, 0.f};

  const int nkt = Kc >> 6;
  for (int kt = 0; kt < nkt; ++kt) {
    const size_t ko = (size_t)kt * 128;  // BK=64 bf16 = 128 B
#pragma unroll
    for (int q = 0; q < 4; ++q)
      gload_lds16(Ag + (size_t)(w * 4 + q) * 8 * K * 2 + srcoff + ko, &As[(w * 4 + q) * 512]);
#pragma unroll
    for (int q = 0; q < 4; ++q)
      gload_lds16(Bg + (size_t)(w * 4 + q) * 8 * K * 2 + srcoff + ko, &Bs[(w * 4 + q) * 512]);
    __syncthreads();
#pragma unroll
    for (int ks = 0; ks < 2; ++ks) {
      short8 a[4], b[4];
#pragma unroll
      for (int mi = 0; mi < 4; ++mi) {
        const int ar = wr + mi * 16 + l15;
        a[mi] = *(const short8*)((const char*)As + (size_t)ar * 128 +
                                 ((((ks << 2) | lhi) ^ (ar & 7)) << 4));
      }
#pragma unroll
      for (int ni = 0; ni < 4; ++ni) {
        const int br = wc + ni * 16 + l15;
        b[ni] = *(const short8*)((const char*)Bs + (size_t)br * 128 +
                                 ((((ks << 2) | lhi) ^ (br & 7)) << 4));
      }
#pragma unroll
      for (int mi = 0; mi < 4; ++mi)
#pragma unroll
        for (int ni = 0; ni < 4; ++ni)
          acc[mi][ni] = __builtin_amdgcn_mfma_f32_16x16x32_bf16(a[mi], b[ni],
                                                                acc[mi][ni], 0, 0, 0);
    }
    __syncthreads();
  }

  const int m0 = mtile * 128 + wr + lhi * 4;
  const int n0 = ntile * 128 + wc + l15;
#pragma unroll
  for (int mi = 0; mi < 4; ++mi) {
    const int m = m0 + mi * 16;
    f32x4 cv, pv;
    if (SCALE) {
      cv = *(const f32x4*)&cbuf[m];
      pv = *(const f32x4*)&p2buf[m];
    }
#pragma unroll
    for (int ni = 0; ni < 4; ++ni) {
      const int n = n0 + ni * 16;
#pragma unroll
      for (int r = 0; r < 4; ++r) {
        float v = acc[mi][ni][r];
        if (SCALE) v *= ((n & 1) ? pv[r] : cv[r]);
        atomicAdd(&out[(size_t)(m + r) * Nn + n], v);
      }
    }
  }
}

// --------------- scaleT: Zt[f][m] = Z[m][2f] + Z[m][2f+1]  (Z already scaled)
// LDS transpose, 16B coalesced stores.
__global__ __launch_bounds__(256) void scaleT_k(const float* __restrict__ Z,
                                                unsigned short* __restrict__ Zt) {
  __shared__ unsigned short zt[64][72];
  const int t = threadIdx.x;
  const int r = t >> 2, q = t & 3;
  const int m = blockIdx.y * 64 + r;
  const int n0 = blockIdx.x * 128;
  const float* p = Z + (size_t)m * 512 + n0;
  float acc[16];
#pragma unroll
  for (int i = 0; i < 8; ++i) {
    float4 v = *(const float4*)&p[q * 4 + i * 16];  // (x_f, y_f, x_{f+1}, y_{f+1}) scaled
    acc[2 * i + 0] = v.x + v.y;
    acc[2 * i + 1] = v.z + v.w;
  }
#pragma unroll
  for (int i = 0; i < 8; ++i) {
    int f = q * 2 + i * 8;
    zt[f + 0][r] = f2bf(acc[2 * i + 0]);
    zt[f + 1][r] = f2bf(acc[2 * i + 1]);
  }
  __syncthreads();
  const int f2 = t >> 2;
  const int gf = blockIdx.x * 64 + f2;
#pragma unroll
  for (int w = 0; w < 2; ++w) {
    int js = q * 8 + w * 32;
    ushort8v u = *(const ushort8v*)&zt[f2][js];
    *(ushort8v*)&Zt[(size_t)gf * N_NODES + blockIdx.y * 64 + js] = u;
  }
}

extern "C" void kernel_launch(void* const* d_in, const int* in_sizes, int n_in,
                              void* d_out, int out_size, void* d_ws, size_t ws_size,
                              hipStream_t stream) {
  const float* x   = (const float*)d_in[0];
  const float* y   = (const float*)d_in[1];
  const float* tp  = (const float*)d_in[2];
  const float* lam = (const float*)d_in[3];
  const float* V   = (const float*)d_in[4];

  char* w = (char*)d_ws;
  unsigned short* Vbf  = (unsigned short*)w; w += (size_t)N_NODES * N_NODES * 2;
  unsigned short* Vtbf = (unsigned short*)w; w += (size_t)N_NODES * N_NODES * 2;
  unsigned short* S2T  = (unsigned short*)w; w += (size_t)512 * N_NODES * 2;
  unsigned short* Zt   = (unsigned short*)w; w += (size_t)N_FEAT * N_NODES * 2;
  float* Zbuf  = (float*)w; w += (size_t)N_NODES * 512 * 4;  // 8MB f32, atomic-accumulated
  float* cbuf  = (float*)w; w += N_NODES * 4;
  float* p2buf = (float*)w; w += N_NODES * 4;

  hipMemsetAsync(Zbuf, 0, (size_t)N_NODES * 512 * 4, stream);
  hipMemsetAsync(d_out, 0, (size_t)N_NODES * N_FEAT * 4, stream);
  spectrum_k<<<N_NODES / 256, 256, 0, stream>>>(lam, tp, cbuf, p2buf);
  prep_all_k<<<4096 + 256, 256, 0, stream>>>(V, x, y, Vbf, Vtbf, S2T);
  // GEMM1: Z[i][s] += c/p2-scaled Vt[i,k-chunk].S2T[s,k-chunk]  (z=8, Kc=512, NTB=2)
  gemm_swz<2, true><<<1024, 256, 0, stream>>>(Vtbf, S2T, Zbuf, cbuf, p2buf,
                                              N_NODES, 512, 512);
  scaleT_k<<<dim3(512 / 128, N_NODES / 64), 256, 0, stream>>>(Zbuf, Zt);
  // GEMM2: out[j][f] += Vbf[j,k-chunk].Zt[f,k-chunk]  (z=16, Kc=256, NTB=1)
  gemm_swz<1, false><<<1024, 256, 0, stream>>>(Vbf, Zt, (float*)d_out, nullptr, nullptr,
                                               N_NODES, 256, N_FEAT);
}

// Round 9
// 178.884 us; speedup vs baseline: 1.4181x; 1.4181x over previous
//
#include <hip/hip_runtime.h>

typedef __attribute__((ext_vector_type(8))) short short8;
typedef __attribute__((ext_vector_type(8))) unsigned short ushort8v;
typedef __attribute__((ext_vector_type(4))) float f32x4;

#define N_NODES 4096
#define N_FEAT  256

__device__ __forceinline__ unsigned short f2bf(float f) {
  union { float f; unsigned u; } a; a.f = f;
  unsigned r = a.u + 0x7FFFu + ((a.u >> 16) & 1u);  // round-to-nearest-even
  return (unsigned short)(r >> 16);
}

__device__ __forceinline__ float bf2f(unsigned short u) {
  union { unsigned u; float f; } a; a.u = ((unsigned)u) << 16;
  return a.f;
}

__device__ __forceinline__ void gload_lds16(const void* g, void* l) {
  __builtin_amdgcn_global_load_lds(
      (const __attribute__((address_space(1))) void*)g,
      (__attribute__((address_space(3))) void*)l, 16, 0, 0);
}

// ---------------------------------------------------------------- spectrum
__global__ void spectrum_k(const float* __restrict__ lam, const float* __restrict__ tp,
                           float* __restrict__ cbuf, float* __restrict__ p2buf) {
  int i = blockIdx.x * 256 + threadIdx.x;
  float tv = tp[0];
  float s = sqrtf(fmaxf(lam[i], 0.f));
  cbuf[i] = cosf(tv * s);
  p2buf[i] = (s < 1e-5f) ? tv : (sinf(tv * s) / s);
}

// ---------------- fused prep: blocks [0,4096) do V->Vbf+Vt; [4096,4352) do x,y->S2T
__global__ __launch_bounds__(256) void prep_all_k(const float* __restrict__ V,
                                                  const float* __restrict__ x,
                                                  const float* __restrict__ y,
                                                  unsigned short* __restrict__ Vbf,
                                                  unsigned short* __restrict__ Vt,
                                                  unsigned short* __restrict__ S2T) {
  __shared__ unsigned short smem[2][64][72];
  const int t = threadIdx.x;
  const int r = t >> 2, q = t & 3;
  const unsigned b = blockIdx.x;
  if (b < 4096u) {
    const int bx = b & 63, by = b >> 6;
    const int gr = by * 64 + r;
    const int gc0 = bx * 64;
#pragma unroll
    for (int i = 0; i < 4; ++i) {
      int c = q * 4 + i * 16;
      float4 v = *(const float4*)&V[(size_t)gr * N_NODES + gc0 + c];
      ushort4 u; u.x = f2bf(v.x); u.y = f2bf(v.y); u.z = f2bf(v.z); u.w = f2bf(v.w);
      *(ushort4*)&Vbf[(size_t)gr * N_NODES + gc0 + c] = u;
      smem[0][c + 0][r] = u.x; smem[0][c + 1][r] = u.y;
      smem[0][c + 2][r] = u.z; smem[0][c + 3][r] = u.w;
    }
    __syncthreads();
    const int r2 = t >> 2;
#pragma unroll
    for (int j = 0; j < 2; ++j) {
      int ms = q * 8 + j * 32;
      ushort8v u = *(const ushort8v*)&smem[0][r2][ms];
      *(ushort8v*)&Vt[(size_t)(gc0 + r2) * N_NODES + by * 64 + ms] = u;
    }
  } else {
    const unsigned b2 = b - 4096u;
    const int bx = b2 & 3, by = b2 >> 2;
    const int gj = by * 64 + r;
    const int gf0 = bx * 64;
#pragma unroll
    for (int i = 0; i < 4; ++i) {
      int c = q * 4 + i * 16;
      float4 vx = *(const float4*)&x[(size_t)gj * N_FEAT + gf0 + c];
      float4 vy = *(const float4*)&y[(size_t)gj * N_FEAT + gf0 + c];
      smem[0][c + 0][r] = f2bf(vx.x); smem[0][c + 1][r] = f2bf(vx.y);
      smem[0][c + 2][r] = f2bf(vx.z); smem[0][c + 3][r] = f2bf(vx.w);
      smem[1][c + 0][r] = f2bf(vy.x); smem[1][c + 1][r] = f2bf(vy.y);
      smem[1][c + 2][r] = f2bf(vy.z); smem[1][c + 3][r] = f2bf(vy.w);
    }
    __syncthreads();
    const int f2 = t >> 2;
#pragma unroll
    for (int j = 0; j < 2; ++j) {
      int js = q * 8 + j * 32;
      ushort8v ux = *(const ushort8v*)&smem[0][f2][js];
      ushort8v uy = *(const ushort8v*)&smem[1][f2][js];
      *(ushort8v*)&S2T[(size_t)(2 * (gf0 + f2) + 0) * N_NODES + by * 64 + js] = ux;
      *(ushort8v*)&S2T[(size_t)(2 * (gf0 + f2) + 1) * N_NODES + by * 64 + js] = uy;
    }
  }
}

// --------------------------------------------------------------- split-K GEMM
// BM=128, BN=128, BK=64, 256 threads (4 waves 2x2), wave tile 64x64 (acc[4][4]).
// Single-buffered LDS (32 KB), 4 blocks/CU. XOR slot-swizzle via pre-swizzled
// global source (LDS dest linear for global_load_lds). XCD-bijective remap.
// SCALE=true (gemm1): epilogue applies c[m]/p2[m], pair-sums (x,y) columns via
// shfl_xor, LDS-transposes (XOR-swizzled chunks in reused As) and writes
// coalesced z-slice rows Z2[zz][f][i] bf16. SCALE=false (gemm2): plain bf16
// partial store part[zz][m][n].
template <int NTB, bool SCALE>
__global__ __launch_bounds__(256, 4) void gemm_swz(const unsigned short* __restrict__ A,
                                                   const unsigned short* __restrict__ B,
                                                   unsigned short* __restrict__ outp,
                                                   const float* __restrict__ cbuf,
                                                   const float* __restrict__ p2buf,
                                                   int K, int Kc, int Nn, size_t MN) {
  __shared__ unsigned short As[128 * 64];
  __shared__ unsigned short Bs[128 * 64];
  const int t = threadIdx.x;
  const int lane = t & 63, w = t >> 6;

  const unsigned L = blockIdx.x;
  const unsigned cx = L & 7u, j = L >> 3u;
  const unsigned ntile = j & ((1u << NTB) - 1u);
  const unsigned GPX = (gridDim.x >> 3) >> NTB;
  const unsigned group = cx * GPX + (j >> NTB);
  const unsigned mtile = group & 31u;
  const unsigned zz = group >> 5u;

  const int wr = (w >> 1) * 64;
  const int wc = (w & 1) * 64;
  const int l15 = lane & 15;
  const int lhi = lane >> 4;

  const size_t kbase = (size_t)zz * Kc;
  const size_t srcoff = (size_t)(lane >> 3) * K * 2 + (size_t)(((lane & 7) ^ (lane >> 3)) << 4);

  const char* Ag = (const char*)(A + (size_t)mtile * 128 * K + kbase);
  const char* Bg = (const char*)(B + (size_t)ntile * 128 * K + kbase);

  f32x4 acc[4][4];
#pragma unroll
  for (int mi = 0; mi < 4; ++mi)
#pragma unroll
    for (int ni = 0; ni < 4; ++ni) acc[mi][ni] = (f32x4){0.f, 0.f, 0.f, 0.f};

  const int nkt = Kc >> 6;
  for (int kt = 0; kt < nkt; ++kt) {
    const size_t ko = (size_t)kt * 128;  // BK=64 bf16 = 128 B
#pragma unroll
    for (int q = 0; q < 4; ++q)
      gload_lds16(Ag + (size_t)(w * 4 + q) * 8 * K * 2 + srcoff + ko, &As[(w * 4 + q) * 512]);
#pragma unroll
    for (int q = 0; q < 4; ++q)
      gload_lds16(Bg + (size_t)(w * 4 + q) * 8 * K * 2 + srcoff + ko, &Bs[(w * 4 + q) * 512]);
    __syncthreads();
#pragma unroll
    for (int ks = 0; ks < 2; ++ks) {
      short8 a[4], b[4];
#pragma unroll
      for (int mi = 0; mi < 4; ++mi) {
        const int ar = wr + mi * 16 + l15;
        a[mi] = *(const short8*)((const char*)As + (size_t)ar * 128 +
                                 ((((ks << 2) | lhi) ^ (ar & 7)) << 4));
      }
#pragma unroll
      for (int ni = 0; ni < 4; ++ni) {
        const int br = wc + ni * 16 + l15;
        b[ni] = *(const short8*)((const char*)Bs + (size_t)br * 128 +
                                 ((((ks << 2) | lhi) ^ (br & 7)) << 4));
      }
#pragma unroll
      for (int mi = 0; mi < 4; ++mi)
#pragma unroll
        for (int ni = 0; ni < 4; ++ni)
          acc[mi][ni] = __builtin_amdgcn_mfma_f32_16x16x32_bf16(a[mi], b[ni],
                                                                acc[mi][ni], 0, 0, 0);
    }
    __syncthreads();
  }

  const int m0 = mtile * 128 + wr + lhi * 4;
  if (SCALE) {
    // ---- fused scale + (x,y) pair-sum + LDS transpose -> Z2[zz][f][i] bf16
    unsigned short* tb = As;  // 64 f x 128 i (8192 shorts), chunk-XOR swizzled
#pragma unroll
    for (int mi = 0; mi < 4; ++mi) {
      const int m = m0 + mi * 16;
      f32x4 cv = *(const f32x4*)&cbuf[m];
      f32x4 pv = *(const f32x4*)&p2buf[m];
      const int mloc = wr + lhi * 4 + mi * 16;
#pragma unroll
      for (int ni = 0; ni < 4; ++ni) {
        float z[4];
#pragma unroll
        for (int r = 0; r < 4; ++r) {
          float own = acc[mi][ni][r];
          float oth = __shfl_xor(own, 1);
          z[r] = cv[r] * own + pv[r] * oth;  // valid on even lanes (own=x, oth=y)
        }
        if (!(lane & 1)) {
          const int floc = (wc >> 1) + (l15 >> 1) + ni * 8;
          const int cm = (mloc >> 2) ^ ((floc & 7) << 2);
          ushort4 u; u.x = f2bf(z[0]); u.y = f2bf(z[1]); u.z = f2bf(z[2]); u.w = f2bf(z[3]);
          *(ushort4*)&tb[floc * 128 + cm * 4] = u;
        }
      }
    }
    __syncthreads();
    unsigned short* Zs = outp + (size_t)zz * MN + (size_t)(ntile * 64) * N_NODES + mtile * 128;
    const int fl = t >> 2, seg = t & 3;
#pragma unroll
    for (int jj = 0; jj < 4; ++jj) {
      const int c = (seg * 8 + jj * 2) ^ ((fl & 7) << 2);
      ushort8v u = *(const ushort8v*)&tb[fl * 128 + c * 4];
      *(ushort8v*)&Zs[(size_t)fl * N_NODES + seg * 32 + jj * 8] = u;
    }
  } else {
    unsigned short* po = outp + (size_t)zz * MN;
    const int n0 = ntile * 128 + wc + l15;
#pragma unroll
    for (int mi = 0; mi < 4; ++mi)
#pragma unroll
      for (int ni = 0; ni < 4; ++ni)
#pragma unroll
        for (int r = 0; r < 4; ++r)
          po[(size_t)(m0 + mi * 16 + r) * Nn + n0 + ni * 16] = f2bf(acc[mi][ni][r]);
  }
}

// --------------- reduce1: Zt[e] = bf16(sum_{z<8} Z2[z][e])  (elementwise, coalesced)
__global__ __launch_bounds__(256) void reduce1_k(const unsigned short* __restrict__ Z2,
                                                 unsigned short* __restrict__ Zt) {
  const size_t e = ((size_t)blockIdx.x * 256 + threadIdx.x) * 8;
  float s[8];
#pragma unroll
  for (int i = 0; i < 8; ++i) s[i] = 0.f;
#pragma unroll
  for (int ks = 0; ks < 8; ++ks) {
    ushort8v u = *(const ushort8v*)&Z2[(size_t)ks * N_FEAT * N_NODES + e];
#pragma unroll
    for (int i = 0; i < 8; ++i) s[i] += bf2f(u[i]);
  }
  ushort8v o;
#pragma unroll
  for (int i = 0; i < 8; ++i) o[i] = f2bf(s[i]);
  *(ushort8v*)&Zt[e] = o;
}

// --------------- reduce2: out[e] = sum_{ks<16} part[ks][e]  (bf16 partials -> f32)
__global__ __launch_bounds__(256) void reduce2_k(const unsigned short* __restrict__ part,
                                                 float* __restrict__ out) {
  const size_t e = ((size_t)blockIdx.x * 256 + threadIdx.x) * 4;
  float4 s = {0.f, 0.f, 0.f, 0.f};
#pragma unroll
  for (int ks = 0; ks < 16; ++ks) {
    ushort4 u = *(const ushort4*)&part[(size_t)ks * N_NODES * N_FEAT + e];
    s.x += bf2f(u.x); s.y += bf2f(u.y); s.z += bf2f(u.z); s.w += bf2f(u.w);
  }
  *(float4*)&out[e] = s;
}

extern "C" void kernel_launch(void* const* d_in, const int* in_sizes, int n_in,
                              void* d_out, int out_size, void* d_ws, size_t ws_size,
                              hipStream_t stream) {
  const float* x   = (const float*)d_in[0];
  const float* y   = (const float*)d_in[1];
  const float* tp  = (const float*)d_in[2];
  const float* lam = (const float*)d_in[3];
  const float* V   = (const float*)d_in[4];

  char* w = (char*)d_ws;
  unsigned short* Vbf  = (unsigned short*)w; w += (size_t)N_NODES * N_NODES * 2;
  unsigned short* Vtbf = (unsigned short*)w; w += (size_t)N_NODES * N_NODES * 2;
  unsigned short* S2T  = (unsigned short*)w; w += (size_t)512 * N_NODES * 2;
  unsigned short* Zt   = (unsigned short*)w; w += (size_t)N_FEAT * N_NODES * 2;
  float* cbuf  = (float*)w; w += N_NODES * 4;
  float* p2buf = (float*)w; w += N_NODES * 4;
  // Z2 (8 x 2MB, gemm1 slices) and partb (16 x 2MB, gemm2 slices) aliased:
  unsigned short* partb = (unsigned short*)w;  // 32MB

  spectrum_k<<<N_NODES / 256, 256, 0, stream>>>(lam, tp, cbuf, p2buf);
  prep_all_k<<<4096 + 256, 256, 0, stream>>>(V, x, y, Vbf, Vtbf, S2T);
  // GEMM1: Z2[z][f][i] = scaled+pair-summed Vt.S2T slice  (z=8, Kc=512, NTB=2)
  gemm_swz<2, true><<<1024, 256, 0, stream>>>(Vtbf, S2T, partb, cbuf, p2buf,
                                              N_NODES, 512, 512,
                                              (size_t)N_FEAT * N_NODES);
  reduce1_k<<<(N_FEAT * N_NODES) / 2048, 256, 0, stream>>>(partb, Zt);
  // GEMM2: part[z][j][f] = Vbf[j, z-chunk] . Zt[f, z-chunk]  (z=16, Kc=256, NTB=1)
  gemm_swz<1, false><<<1024, 256, 0, stream>>>(Vbf, Zt, partb, nullptr, nullptr,
                                               N_NODES, 256, N_FEAT,
                                               (size_t)N_NODES * N_FEAT);
  reduce2_k<<<(N_NODES * N_FEAT) / 1024, 256, 0, stream>>>(partb, (float*)d_out);
}

// Round 10
// 174.920 us; speedup vs baseline: 1.4503x; 1.0227x over previous
//
#include <hip/hip_runtime.h>

typedef __attribute__((ext_vector_type(8))) short short8;
typedef __attribute__((ext_vector_type(8))) unsigned short ushort8v;
typedef __attribute__((ext_vector_type(4))) float f32x4;

#define N_NODES 4096
#define N_FEAT  256

__device__ __forceinline__ unsigned short f2bf(float f) {
  union { float f; unsigned u; } a; a.f = f;
  unsigned r = a.u + 0x7FFFu + ((a.u >> 16) & 1u);  // round-to-nearest-even
  return (unsigned short)(r >> 16);
}

__device__ __forceinline__ float bf2f(unsigned short u) {
  union { unsigned u; float f; } a; a.u = ((unsigned)u) << 16;
  return a.f;
}

__device__ __forceinline__ void gload_lds16(const void* g, void* l) {
  __builtin_amdgcn_global_load_lds(
      (const __attribute__((address_space(1))) void*)g,
      (__attribute__((address_space(3))) void*)l, 16, 0, 0);
}

// ---------------- fused prep: blocks [0,4096) do V->Vbf+Vt; [4096,4352) do x,y->S2T
__global__ __launch_bounds__(256) void prep_all_k(const float* __restrict__ V,
                                                  const float* __restrict__ x,
                                                  const float* __restrict__ y,
                                                  unsigned short* __restrict__ Vbf,
                                                  unsigned short* __restrict__ Vt,
                                                  unsigned short* __restrict__ S2T) {
  __shared__ unsigned short smem[2][64][72];
  const int t = threadIdx.x;
  const int r = t >> 2, q = t & 3;
  const unsigned b = blockIdx.x;
  if (b < 4096u) {
    const int bx = b & 63, by = b >> 6;
    const int gr = by * 64 + r;
    const int gc0 = bx * 64;
#pragma unroll
    for (int i = 0; i < 4; ++i) {
      int c = q * 4 + i * 16;
      float4 v = *(const float4*)&V[(size_t)gr * N_NODES + gc0 + c];
      ushort4 u; u.x = f2bf(v.x); u.y = f2bf(v.y); u.z = f2bf(v.z); u.w = f2bf(v.w);
      *(ushort4*)&Vbf[(size_t)gr * N_NODES + gc0 + c] = u;
      smem[0][c + 0][r] = u.x; smem[0][c + 1][r] = u.y;
      smem[0][c + 2][r] = u.z; smem[0][c + 3][r] = u.w;
    }
    __syncthreads();
    const int r2 = t >> 2;
#pragma unroll
    for (int j = 0; j < 2; ++j) {
      int ms = q * 8 + j * 32;
      ushort8v u = *(const ushort8v*)&smem[0][r2][ms];
      *(ushort8v*)&Vt[(size_t)(gc0 + r2) * N_NODES + by * 64 + ms] = u;
    }
  } else {
    const unsigned b2 = b - 4096u;
    const int bx = b2 & 3, by = b2 >> 2;
    const int gj = by * 64 + r;
    const int gf0 = bx * 64;
#pragma unroll
    for (int i = 0; i < 4; ++i) {
      int c = q * 4 + i * 16;
      float4 vx = *(const float4*)&x[(size_t)gj * N_FEAT + gf0 + c];
      float4 vy = *(const float4*)&y[(size_t)gj * N_FEAT + gf0 + c];
      smem[0][c + 0][r] = f2bf(vx.x); smem[0][c + 1][r] = f2bf(vx.y);
      smem[0][c + 2][r] = f2bf(vx.z); smem[0][c + 3][r] = f2bf(vx.w);
      smem[1][c + 0][r] = f2bf(vy.x); smem[1][c + 1][r] = f2bf(vy.y);
      smem[1][c + 2][r] = f2bf(vy.z); smem[1][c + 3][r] = f2bf(vy.w);
    }
    __syncthreads();
    const int f2 = t >> 2;
#pragma unroll
    for (int j = 0; j < 2; ++j) {
      int js = q * 8 + j * 32;
      ushort8v ux = *(const ushort8v*)&smem[0][f2][js];
      ushort8v uy = *(const ushort8v*)&smem[1][f2][js];
      *(ushort8v*)&S2T[(size_t)(2 * (gf0 + f2) + 0) * N_NODES + by * 64 + js] = ux;
      *(ushort8v*)&S2T[(size_t)(2 * (gf0 + f2) + 1) * N_NODES + by * 64 + js] = uy;
    }
  }
}

// --------------------------------------------------------------- split-K GEMM
// BM=128, BN=128, BK=64, 256 threads (4 waves 2x2), wave tile 64x64 (acc[4][4]).
// Single-buffered LDS (32 KB), 4 blocks/CU. XOR slot-swizzle via pre-swizzled
// global source (LDS dest linear for global_load_lds). XCD-bijective remap:
// L%8 = xcd owns contiguous (mtile,z) groups; ntile-sharers of an A-panel are
// co-resident on one XCD; the z-chunk of A fits that XCD's 4MB L2.
// Partials stored bf16.
template <int NTB>
__global__ __launch_bounds__(256, 4) void gemm_swz(const unsigned short* __restrict__ A,
                                                   const unsigned short* __restrict__ B,
                                                   unsigned short* __restrict__ part,
                                                   int K, int Kc, int Nn, size_t MN) {
  __shared__ unsigned short As[128 * 64];
  __shared__ unsigned short Bs[128 * 64];
  const int t = threadIdx.x;
  const int lane = t & 63, w = t >> 6;

  const unsigned L = blockIdx.x;
  const unsigned cx = L & 7u, j = L >> 3u;
  const unsigned ntile = j & ((1u << NTB) - 1u);
  const unsigned GPX = (gridDim.x >> 3) >> NTB;
  const unsigned group = cx * GPX + (j >> NTB);
  const unsigned mtile = group & 31u;
  const unsigned zz = group >> 5u;

  const int wr = (w >> 1) * 64;
  const int wc = (w & 1) * 64;
  const int l15 = lane & 15;
  const int lhi = lane >> 4;

  const size_t kbase = (size_t)zz * Kc;
  // pre-swizzled per-lane source offset (bytes): row lane>>3, k-slot (lane&7)^(lane>>3)
  const size_t srcoff = (size_t)(lane >> 3) * K * 2 + (size_t)(((lane & 7) ^ (lane >> 3)) << 4);

  const char* Ag = (const char*)(A + (size_t)mtile * 128 * K + kbase);
  const char* Bg = (const char*)(B + (size_t)ntile * 128 * K + kbase);

  f32x4 acc[4][4];
#pragma unroll
  for (int mi = 0; mi < 4; ++mi)
#pragma unroll
    for (int ni = 0; ni < 4; ++ni) acc[mi][ni] = (f32x4){0.f, 0.f, 0.f, 0.f};

  const int nkt = Kc >> 6;
  for (int kt = 0; kt < nkt; ++kt) {
    const size_t ko = (size_t)kt * 128;  // BK=64 bf16 = 128 B
#pragma unroll
    for (int q = 0; q < 4; ++q)
      gload_lds16(Ag + (size_t)(w * 4 + q) * 8 * K * 2 + srcoff + ko, &As[(w * 4 + q) * 512]);
#pragma unroll
    for (int q = 0; q < 4; ++q)
      gload_lds16(Bg + (size_t)(w * 4 + q) * 8 * K * 2 + srcoff + ko, &Bs[(w * 4 + q) * 512]);
    __syncthreads();
#pragma unroll
    for (int ks = 0; ks < 2; ++ks) {
      short8 a[4], b[4];
#pragma unroll
      for (int mi = 0; mi < 4; ++mi) {
        const int ar = wr + mi * 16 + l15;
        a[mi] = *(const short8*)((const char*)As + (size_t)ar * 128 +
                                 ((((ks << 2) | lhi) ^ (ar & 7)) << 4));
      }
#pragma unroll
      for (int ni = 0; ni < 4; ++ni) {
        const int br = wc + ni * 16 + l15;
        b[ni] = *(const short8*)((const char*)Bs + (size_t)br * 128 +
                                 ((((ks << 2) | lhi) ^ (br & 7)) << 4));
      }
#pragma unroll
      for (int mi = 0; mi < 4; ++mi)
#pragma unroll
        for (int ni = 0; ni < 4; ++ni)
          acc[mi][ni] = __builtin_amdgcn_mfma_f32_16x16x32_bf16(a[mi], b[ni],
                                                                acc[mi][ni], 0, 0, 0);
    }
    __syncthreads();
  }

  unsigned short* po = part + (size_t)zz * MN;
  const int m0 = mtile * 128 + wr + lhi * 4;
  const int n0 = ntile * 128 + wc + l15;
#pragma unroll
  for (int mi = 0; mi < 4; ++mi)
#pragma unroll
    for (int ni = 0; ni < 4; ++ni)
#pragma unroll
      for (int r = 0; r < 4; ++r)
        po[(size_t)(m0 + mi * 16 + r) * Nn + n0 + ni * 16] = f2bf(acc[mi][ni][r]);
}

// --------------- reduce1: Zt[f][m] = c[m]*sum_ks part[ks][m][2f] + p2[m]*sum_ks part[ks][m][2f+1]
// spectrum (cos/sinc) computed inline; LDS transpose; 16B coalesced stores.
__global__ __launch_bounds__(256) void reduce1_k(const unsigned short* __restrict__ part,
                                                 const float* __restrict__ lam,
                                                 const float* __restrict__ tp,
                                                 unsigned short* __restrict__ Zt) {
  __shared__ unsigned short zt[64][72];
  const int t = threadIdx.x;
  const int r = t >> 2, q = t & 3;
  const int m = blockIdx.y * 64 + r;
  const int n0 = blockIdx.x * 128;
  const float tv = tp[0];
  const float s = sqrtf(fmaxf(lam[m], 0.f));
  const float cv = cosf(tv * s);
  const float pv = (s < 1e-5f) ? tv : (sinf(tv * s) / s);
  float acc[16];
#pragma unroll
  for (int i = 0; i < 16; ++i) acc[i] = 0.f;
  for (int ks = 0; ks < 8; ++ks) {
    const unsigned short* p = part + ((size_t)ks * N_NODES + m) * 512 + n0;
#pragma unroll
    for (int i = 0; i < 8; ++i) {
      ushort4 u = *(const ushort4*)&p[q * 4 + i * 16];  // (x_f, y_f, x_{f+1}, y_{f+1})
      acc[2 * i + 0] += cv * bf2f(u.x) + pv * bf2f(u.y);
      acc[2 * i + 1] += cv * bf2f(u.z) + pv * bf2f(u.w);
    }
  }
#pragma unroll
  for (int i = 0; i < 8; ++i) {
    int f = q * 2 + i * 8;
    zt[f + 0][r] = f2bf(acc[2 * i + 0]);
    zt[f + 1][r] = f2bf(acc[2 * i + 1]);
  }
  __syncthreads();
  const int f2 = t >> 2;
  const int gf = blockIdx.x * 64 + f2;
#pragma unroll
  for (int w = 0; w < 2; ++w) {
    int js = q * 8 + w * 32;
    ushort8v u = *(const ushort8v*)&zt[f2][js];
    *(ushort8v*)&Zt[(size_t)gf * N_NODES + blockIdx.y * 64 + js] = u;
  }
}

// --------------- reduce2: out[e] = sum_{ks<16} part[ks][e]  (bf16 partials -> f32)
__global__ __launch_bounds__(256) void reduce2_k(const unsigned short* __restrict__ part,
                                                 float* __restrict__ out) {
  const size_t e = ((size_t)blockIdx.x * 256 + threadIdx.x) * 8;
  float s[8];
#pragma unroll
  for (int i = 0; i < 8; ++i) s[i] = 0.f;
#pragma unroll
  for (int ks = 0; ks < 16; ++ks) {
    ushort8v u = *(const ushort8v*)&part[(size_t)ks * N_NODES * N_FEAT + e];
#pragma unroll
    for (int i = 0; i < 8; ++i) s[i] += bf2f(u[i]);
  }
#pragma unroll
  for (int i = 0; i < 8; i += 4) {
    float4 o; o.x = s[i]; o.y = s[i + 1]; o.z = s[i + 2]; o.w = s[i + 3];
    *(float4*)&out[e + i] = o;
  }
}

extern "C" void kernel_launch(void* const* d_in, const int* in_sizes, int n_in,
                              void* d_out, int out_size, void* d_ws, size_t ws_size,
                              hipStream_t stream) {
  const float* x   = (const float*)d_in[0];
  const float* y   = (const float*)d_in[1];
  const float* tp  = (const float*)d_in[2];
  const float* lam = (const float*)d_in[3];
  const float* V   = (const float*)d_in[4];

  char* w = (char*)d_ws;
  unsigned short* Vbf  = (unsigned short*)w; w += (size_t)N_NODES * N_NODES * 2;
  unsigned short* Vtbf = (unsigned short*)w; w += (size_t)N_NODES * N_NODES * 2;
  unsigned short* S2T  = (unsigned short*)w; w += (size_t)512 * N_NODES * 2;
  unsigned short* Zt   = (unsigned short*)w; w += (size_t)N_FEAT * N_NODES * 2;
  unsigned short* partb = (unsigned short*)w;  // 32MB bf16, shared by both stages

  prep_all_k<<<4096 + 256, 256, 0, stream>>>(V, x, y, Vbf, Vtbf, S2T);
  // GEMM1: part[z][i][s] = Vt[i, z-chunk] . S2T[s, z-chunk]
  // z=8, Kc=512, BN=128 (4 ntiles, NTB=2); 1024 blocks; zz == xcd (4MB A-chunk per L2)
  gemm_swz<2><<<1024, 256, 0, stream>>>(Vtbf, S2T, partb, N_NODES, 512, 512,
                                        (size_t)N_NODES * 512);
  reduce1_k<<<dim3(512 / 128, N_NODES / 64), 256, 0, stream>>>(partb, lam, tp, Zt);
  // GEMM2: part[z][j][f] = Vbf[j, z-chunk] . Zt[f, z-chunk]
  // z=16, Kc=256, BN=128 (2 ntiles, NTB=1); 1024 blocks; each XCD covers 2 K-chunks
  gemm_swz<1><<<1024, 256, 0, stream>>>(Vbf, Zt, partb, N_NODES, 256, N_FEAT,
                                        (size_t)N_NODES * N_FEAT);
  reduce2_k<<<(N_NODES * N_FEAT) / 2048, 256, 0, stream>>>(partb, (float*)d_out);
}